// Round 3
// baseline (1658.449 us; speedup 1.0000x reference)
//
#include <hip/hip_runtime.h>
#include <hip/hip_bf16.h>
#include <stdint.h>

// Problem constants
#define Bz 64
#define Lz 2048
#define Hz 1024
#define Uz 1024
#define Vz 32000
#define Ez 256

typedef __attribute__((ext_vector_type(8))) short bf16x8;
typedef __attribute__((ext_vector_type(4))) float f32x4;
typedef __attribute__((ext_vector_type(16))) float f32x16;

__device__ __forceinline__ unsigned short f2bf(float f) {
    unsigned int u = __float_as_uint(f);
    u += 0x7fffu + ((u >> 16) & 1u);   // round-to-nearest-even
    return (unsigned short)(u >> 16);
}

__device__ __forceinline__ float tanh_fast(float x) {
    float e = __expf(2.0f * x);
    return (e - 1.0f) * __builtin_amdgcn_rcpf(e + 1.0f);
}

__device__ __forceinline__ void async_cp16(const void* g, void* l) {
    __builtin_amdgcn_global_load_lds(
        (const __attribute__((address_space(1))) void*)g,
        (__attribute__((address_space(3))) void*)l, 16, 0, 0);
}

// ---------------------------------------------------------------------------
// K0: pack w1 (H x U fp32, [k][n]) into bf16 slabs for the 32x32x16 score
// kernel: w1p[kt(16)][n(1024)][8 phys chunks x 8 bf16], where phys chunk p of
// row n holds logical chunk c = p ^ (n&7) (XOR swizzle -> conflict-free
// ds_read_b128), logical chunk c covering k = kt*64 + c*8 + j.
__global__ void pack_w1_kernel(const float* __restrict__ w1,
                               unsigned short* __restrict__ w1p) {
    __shared__ unsigned short tb[64][264];
    int nb = blockIdx.x, kt = blockIdx.y, t = threadIdx.x;
#pragma unroll
    for (int i = 0; i < 64; ++i)
        tb[i][t] = f2bf(w1[(size_t)(kt * 64 + i) * Uz + nb * 256 + t]);
    __syncthreads();
    int n = nb * 256 + t;
    unsigned short* dst = w1p + (size_t)kt * 65536 + (size_t)n * 64;
#pragma unroll
    for (int p = 0; p < 8; ++p) {
        int c = p ^ (n & 7);
        union { uint4 v; unsigned short s[8]; } u;
#pragma unroll
        for (int j = 0; j < 8; ++j) u.s[j] = tb[c * 8 + j][t];
        *(uint4*)(dst + p * 8) = u.v;
    }
}

// ---------------------------------------------------------------------------
// K1a: transpose hidden (64 x 1024) -> hiddenT (1024 x 64).
__global__ void transpose_hidden_kernel(const float* __restrict__ hidden,
                                        float* __restrict__ hT) {
    __shared__ float tile[64][65];
    int cb = blockIdx.x;
    int t  = threadIdx.x;
    int tc = t & 63, tr = t >> 6;
#pragma unroll
    for (int i = 0; i < 16; ++i) {
        int r = i * 4 + tr;
        tile[r][tc] = hidden[(size_t)r * Uz + cb * 64 + tc];
    }
    __syncthreads();
#pragma unroll
    for (int i = 0; i < 16; ++i) {
        int k = i * 4 + tr;
        hT[(size_t)(cb * 64 + k) * 64 + tc] = tile[tc][k];
    }
}

// K1b: hid = hidden @ w2, skinny-M GEMM, K-split x16 + atomicAdd.
__global__ __launch_bounds__(256)
void hid_gemm_kernel(const float* __restrict__ hT, const float* __restrict__ w2,
                     float* __restrict__ hid) {
    int col = blockIdx.x * 256 + threadIdx.x;
    int k0  = blockIdx.y * 64;
    float acc[64];
#pragma unroll
    for (int r = 0; r < 64; ++r) acc[r] = 0.f;
#pragma unroll 4
    for (int k = 0; k < 64; ++k) {
        float w = w2[(size_t)(k0 + k) * Uz + col];
        const float* srow = hT + (size_t)(k0 + k) * 64;
#pragma unroll
        for (int r = 0; r < 64; ++r) acc[r] = fmaf(srow[r], w, acc[r]);
    }
#pragma unroll
    for (int r = 0; r < 64; ++r) atomicAdd(&hid[(size_t)r * Uz + col], acc[r]);
}

// ---------------------------------------------------------------------------
// K2: fused score kernel, v2: mfma_f32_32x32x16_bf16, block tile 128x128,
// wave tile 64x64 (2x2 tiles of 32x32 -> 64 AGPR), BK=64 (4 k-steps/period),
// bf16 LDS tiles 16+16 KB, XOR-chunk swizzle, 4 blocks/CU target.
// scores[b,l] = sum_n tanh(enc@w1 + b1 + b2 + hid)[l,n] * vw[n], atomicAdd
// over 8 N-blocks.
__global__ __launch_bounds__(256, 4)
void score_kernel(const float* __restrict__ enc,
                  const unsigned short* __restrict__ w1p,
                  const float* __restrict__ b1, const float* __restrict__ b2,
                  const float* __restrict__ hid, const float* __restrict__ vw,
                  float* __restrict__ scores) {
    __shared__ __align__(16) unsigned short lA[128 * 64];  // 16 KB bf16, swizzled
    __shared__ __align__(16) unsigned short lB[128 * 64];  // 16 KB bf16, swizzled

    const int t    = threadIdx.x;
    const int lane = t & 63;
    const int wave = t >> 6;
    const int ln   = lane & 31;       // row/col within 32-tile
    const int kh   = lane >> 5;       // k-half select
    const int wm   = wave & 1;        // wave row (64)
    const int wn   = wave >> 1;       // wave col (64)
    const int n0   = blockIdx.x * 128;
    const int m0   = blockIdx.y * 128;
    const int bidx = m0 >> 11;        // batch row (2048 rows per b)
    const int sw   = ln & 7;          // XOR swizzle key (row&7 for frag rows)

    f32x16 acc[2][2];
#pragma unroll
    for (int i = 0; i < 2; ++i)
#pragma unroll
        for (int j = 0; j < 2; ++j)
#pragma unroll
            for (int r = 0; r < 16; ++r) acc[i][j][r] = 0.f;

    // A staging geometry: thread handles phys chunks P = i*256+t (i<4);
    // row m = i*32 + (t>>3), phys-in-row pc = t&7, source logical chunk
    // ca = pc ^ (m&7) (constant across i since i*32 % 8 == 0).
    const int  mrow = t >> 3;
    const int  ca   = (t & 7) ^ (mrow & 7);
    const float* encb = enc + (size_t)(m0 + mrow) * Hz + ca * 8;
    // B staging: linear copy of 16 KB slab (kt, n0..n0+128), 4 chunks/thread.
    const char* w1bb = ((const char*)w1p) + (size_t)n0 * 128 + (size_t)t * 16;

    // Fragment LDS byte bases (row * 128 B)
    const int mA0 = (wm * 64 + ln) * 128, mA1 = mA0 + 32 * 128;
    const int nB0 = (wn * 64 + ln) * 128, nB1 = nB0 + 32 * 128;

    for (int kt = 0; kt < 16; ++kt) {
        __syncthreads();
        // Stage B: async global->LDS, 16B chunks, layout order preserved.
#pragma unroll
        for (int i = 0; i < 4; ++i)
            async_cp16(w1bb + (size_t)kt * 131072 + i * 4096,
                       ((char*)lB) + (i * 256 + t) * 16);
        // Stage A: fp32 loads -> bf16 cvt -> swizzled ds_write_b128.
        float4 f[8];
#pragma unroll
        for (int i = 0; i < 4; ++i) {
            const float* s = encb + (size_t)i * 32 * Hz + kt * 64;
            f[2 * i]     = *(const float4*)(s);
            f[2 * i + 1] = *(const float4*)(s + 4);
        }
#pragma unroll
        for (int i = 0; i < 4; ++i) {
            union { uint4 u; __hip_bfloat162 h[4]; } w;
            w.h[0] = __float22bfloat162_rn(make_float2(f[2*i].x,   f[2*i].y));
            w.h[1] = __float22bfloat162_rn(make_float2(f[2*i].z,   f[2*i].w));
            w.h[2] = __float22bfloat162_rn(make_float2(f[2*i+1].x, f[2*i+1].y));
            w.h[3] = __float22bfloat162_rn(make_float2(f[2*i+1].z, f[2*i+1].w));
            *(uint4*)(((char*)lA) + (i * 256 + t) * 16) = w.u;
        }
        __syncthreads();
        // Compute: 4 k-steps x (2 m-tiles x 2 n-tiles) MFMA.
#pragma unroll
        for (int ks = 0; ks < 4; ++ks) {
            const int off = ((2 * ks + kh) ^ sw) * 16;
            bf16x8 a0 = *(const bf16x8*)(((const char*)lA) + mA0 + off);
            bf16x8 a1 = *(const bf16x8*)(((const char*)lA) + mA1 + off);
            bf16x8 b0 = *(const bf16x8*)(((const char*)lB) + nB0 + off);
            bf16x8 b1f = *(const bf16x8*)(((const char*)lB) + nB1 + off);
            acc[0][0] = __builtin_amdgcn_mfma_f32_32x32x16_bf16(a0, b0,  acc[0][0], 0, 0, 0);
            acc[0][1] = __builtin_amdgcn_mfma_f32_32x32x16_bf16(a0, b1f, acc[0][1], 0, 0, 0);
            acc[1][0] = __builtin_amdgcn_mfma_f32_32x32x16_bf16(a1, b0,  acc[1][0], 0, 0, 0);
            acc[1][1] = __builtin_amdgcn_mfma_f32_32x32x16_bf16(a1, b1f, acc[1][1], 0, 0, 0);
        }
    }

    // Epilogue: tanh + v_w dot, reduce over n (32 lanes per kh-half), atomic.
    // C/D layout (verified): col = lane&31, row = (reg&3) + 8*(reg>>2) + 4*kh.
    const float* hidb = hid + (size_t)bidx * Uz;
#pragma unroll
    for (int mt = 0; mt < 2; ++mt) {
        float ps[16];
#pragma unroll
        for (int r = 0; r < 16; ++r) ps[r] = 0.f;
#pragma unroll
        for (int nt = 0; nt < 2; ++nt) {
            int n = n0 + wn * 64 + nt * 32 + ln;
            float bias = b1[n] + b2[n] + hidb[n];
            float vwn = vw[n];
#pragma unroll
            for (int r = 0; r < 16; ++r)
                ps[r] += tanh_fast(acc[mt][nt][r] + bias) * vwn;
        }
#pragma unroll
        for (int r = 0; r < 16; ++r) {
            float v = ps[r];
            v += __shfl_xor(v, 1);
            v += __shfl_xor(v, 2);
            v += __shfl_xor(v, 4);
            v += __shfl_xor(v, 8);
            v += __shfl_xor(v, 16);
            if (ln == 0) {
                int row = (r & 3) + 8 * (r >> 2) + 4 * kh;
                atomicAdd(&scores[m0 + wm * 64 + mt * 32 + row], v);
            }
        }
    }
}

// ---------------------------------------------------------------------------
// K3: softmax over L per batch row; writes attention_weights to d_out.
__global__ void softmax_kernel(const float* __restrict__ scores,
                               float* __restrict__ attn) {
    int b = blockIdx.x, t = threadIdx.x;
    __shared__ float sm[4], ss[4];
    float v[8];
    float mx = -1e30f;
#pragma unroll
    for (int i = 0; i < 8; ++i) {
        v[i] = scores[b * Lz + i * 256 + t];
        mx = fmaxf(mx, v[i]);
    }
    for (int o = 1; o < 64; o <<= 1) mx = fmaxf(mx, __shfl_xor(mx, o));
    if ((t & 63) == 0) sm[t >> 6] = mx;
    __syncthreads();
    mx = fmaxf(fmaxf(sm[0], sm[1]), fmaxf(sm[2], sm[3]));
    float sum = 0.f;
#pragma unroll
    for (int i = 0; i < 8; ++i) { v[i] = __expf(v[i] - mx); sum += v[i]; }
    for (int o = 1; o < 64; o <<= 1) sum += __shfl_xor(sum, o);
    if ((t & 63) == 0) ss[t >> 6] = sum;
    __syncthreads();
    sum = ss[0] + ss[1] + ss[2] + ss[3];
    float inv = 1.0f / sum;
#pragma unroll
    for (int i = 0; i < 8; ++i) attn[b * Lz + i * 256 + t] = v[i] * inv;
}

// ---------------------------------------------------------------------------
// K4: context[b,h] = sum_l attn[b,l] * enc[b,l,h]. Pure-BW second enc pass.
__global__ void context_kernel(const float* __restrict__ enc,
                               const float* __restrict__ attn,
                               float* __restrict__ ctx) {
    int h  = blockIdx.x * 256 + threadIdx.x;
    int l0 = blockIdx.y * 512;
    int b  = blockIdx.z;
    const float* ep = enc + ((size_t)b * Lz + l0) * Hz + h;
    const float* ap = attn + b * Lz + l0;
    float acc = 0.f;
#pragma unroll 8
    for (int l = 0; l < 512; ++l) acc = fmaf(ap[l], ep[(size_t)l * Hz], acc);
    atomicAdd(&ctx[b * Uz + h], acc);
}

// ---------------------------------------------------------------------------
// K5: GRU with h0 = 0 => state = (1 - sigmoid(zi_z)) * tanh(zi_h).
__global__ void gru_kernel(const int* __restrict__ x,
                           const float* __restrict__ emb,
                           const float* __restrict__ ctx,
                           const float* __restrict__ gk,
                           const float* __restrict__ gb,
                           float* __restrict__ state,
                           float* __restrict__ stateT) {
    int u  = blockIdx.y * 256 + threadIdx.x;
    int b0 = blockIdx.x * 2;
    float az0 = 0, az1 = 0, ah0 = 0, ah1 = 0;
    const float* c0 = ctx + b0 * Uz;
    const float* c1 = c0 + Uz;
    const float* e0 = emb + (size_t)x[b0] * Ez;
    const float* e1 = emb + (size_t)x[b0 + 1] * Ez;
    for (int k = 0; k < Hz; ++k) {
        float wz = gk[(size_t)k * 3072 + u];
        float wh = gk[(size_t)k * 3072 + 2048 + u];
        float x0 = c0[k], x1 = c1[k];
        az0 = fmaf(x0, wz, az0); ah0 = fmaf(x0, wh, ah0);
        az1 = fmaf(x1, wz, az1); ah1 = fmaf(x1, wh, ah1);
    }
    for (int k = 0; k < Ez; ++k) {
        float wz = gk[(size_t)(Hz + k) * 3072 + u];
        float wh = gk[(size_t)(Hz + k) * 3072 + 2048 + u];
        float x0 = e0[k], x1 = e1[k];
        az0 = fmaf(x0, wz, az0); ah0 = fmaf(x0, wh, ah0);
        az1 = fmaf(x1, wz, az1); ah1 = fmaf(x1, wh, ah1);
    }
    float gz = gb[u], gh = gb[2048 + u];
    float z0 = __builtin_amdgcn_rcpf(1.f + __expf(-(az0 + gz)));
    float z1 = __builtin_amdgcn_rcpf(1.f + __expf(-(az1 + gz)));
    float s0 = (1.f - z0) * tanh_fast(ah0 + gh);
    float s1 = (1.f - z1) * tanh_fast(ah1 + gh);
    state[b0 * Uz + u]       = s0;
    state[(b0 + 1) * Uz + u] = s1;
    stateT[(size_t)u * 64 + b0]     = s0;
    stateT[(size_t)u * 64 + b0 + 1] = s1;
}

// ---------------------------------------------------------------------------
// K6: logits = state @ out_w + out_b. Register-blocked 8 rows x 4 cols per
// thread: per k = 3 float4 loads + 32 FMA. K-split x2, atomicAdd.
__global__ __launch_bounds__(256)
void logits_kernel(const float* __restrict__ stateT,
                   const float* __restrict__ ow, const float* __restrict__ ob,
                   float* __restrict__ out) {
    int t  = threadIdx.x;
    int rg = t >> 5;                       // row group: rows rg*8 .. rg*8+7
    int ct = t & 31;
    int c4 = blockIdx.x * 128 + ct * 4;    // 4 consecutive cols
    int k0 = blockIdx.y * 512;
    float acc[8][4];
#pragma unroll
    for (int i = 0; i < 8; ++i)
#pragma unroll
        for (int j = 0; j < 4; ++j) acc[i][j] = 0.f;
    const float4* st4 = (const float4*)stateT;
#pragma unroll 2
    for (int k = 0; k < 512; ++k) {
        int kk = k0 + k;
        float4 w  = *(const float4*)(ow + (size_t)kk * Vz + c4);
        float4 s0 = st4[kk * 16 + rg * 2];
        float4 s1 = st4[kk * 16 + rg * 2 + 1];
        float s[8] = {s0.x, s0.y, s0.z, s0.w, s1.x, s1.y, s1.z, s1.w};
        float wv[4] = {w.x, w.y, w.z, w.w};
#pragma unroll
        for (int i = 0; i < 8; ++i)
#pragma unroll
            for (int j = 0; j < 4; ++j)
                acc[i][j] = fmaf(s[i], wv[j], acc[i][j]);
    }
#pragma unroll
    for (int i = 0; i < 8; ++i) {
        size_t rowo = (size_t)(rg * 8 + i) * Vz + c4;
#pragma unroll
        for (int j = 0; j < 4; ++j) {
            float v = acc[i][j] + ((k0 == 0) ? ob[c4 + j] : 0.f);
            atomicAdd(&out[rowo + j], v);
        }
    }
}

// ---------------------------------------------------------------------------
extern "C" void kernel_launch(void* const* d_in, const int* in_sizes, int n_in,
                              void* d_out, int out_size, void* d_ws, size_t ws_size,
                              hipStream_t stream) {
    const int*   x      = (const int*)d_in[0];
    const float* hidden = (const float*)d_in[1];
    const float* enc    = (const float*)d_in[2];
    const float* emb    = (const float*)d_in[3];
    const float* w1     = (const float*)d_in[4];
    const float* b1     = (const float*)d_in[5];
    const float* w2     = (const float*)d_in[6];
    const float* b2     = (const float*)d_in[7];
    const float* vw     = (const float*)d_in[8];
    // d_in[9] = v_b: softmax is shift-invariant, score is not an output -> unused
    const float* gk     = (const float*)d_in[10];
    // d_in[11] = gru_rk: dead (h0 == 0)
    const float* gb     = (const float*)d_in[12];
    const float* ow     = (const float*)d_in[13];
    const float* ob     = (const float*)d_in[14];

    float* out    = (float*)d_out;
    float* logits = out;                        // 64*32000
    float* state  = out + (size_t)Bz * Vz;      // 64*1024
    float* attn   = state + (size_t)Bz * Uz;    // 64*2048

    char* ws = (char*)d_ws;
    float* scores = (float*)ws;                          // 512 KB
    float* ctx    = (float*)(ws + 524288);               // 256 KB
    float* hid    = (float*)(ws + 786432);               // 256 KB
    unsigned short* w1p = (unsigned short*)(ws + 1048576); // 2 MB bf16-packed w1
    float* stateT = (float*)(ws + 3145728);              // 256 KB
    float* hT     = (float*)(ws + 3407872);              // 256 KB

    // Zero the atomic-accumulated buffers (scores, ctx, hid = first 1 MB) and
    // the logits region of d_out (atomicAdd target).
    hipMemsetAsync(d_ws, 0, 1048576, stream);
    hipMemsetAsync(d_out, 0, (size_t)Bz * Vz * sizeof(float), stream);

    pack_w1_kernel<<<dim3(4, 16), 256, 0, stream>>>(w1, w1p);
    transpose_hidden_kernel<<<16, 256, 0, stream>>>(hidden, hT);
    hid_gemm_kernel<<<dim3(4, 16), 256, 0, stream>>>(hT, w2, hid);
    score_kernel<<<dim3(8, 1024), 256, 0, stream>>>(enc, w1p, b1, b2,
                                                    hid, vw, scores);
    softmax_kernel<<<Bz, 256, 0, stream>>>(scores, attn);
    context_kernel<<<dim3(4, 4, Bz), 256, 0, stream>>>(enc, attn, ctx);
    gru_kernel<<<dim3(Bz / 2, 4), 256, 0, stream>>>(x, emb, ctx, gk, gb, state,
                                                    stateT);
    logits_kernel<<<dim3(250, 2), 256, 0, stream>>>(stateT, ow, ob, logits);
}